// Round 5
// baseline (271.240 us; speedup 1.0000x reference)
//
#include <hip/hip_runtime.h>
#include <hip/hip_bf16.h>
#include <hip/hip_cooperative_groups.h>
#include <math.h>

namespace cg = cooperative_groups;

// Problem constants
#define BB 32
#define SS 2048
#define HH 1024
#define DD 1024
#define HD 2048
#define NSPLIT 32   // 64-row chunks per batch (max)
#define KSPLIT 16   // K-splits for out GEMM
#define NEG_BIG -1e10f

__device__ __forceinline__ float wave_reduce_sum(float v) {
#pragma unroll
    for (int off = 32; off > 0; off >>= 1) v += __shfl_xor(v, off, 64);
    return v;
}

__device__ __forceinline__ float dot4(float4 a, float4 b) {
    return a.x * b.x + a.y * b.y + a.z * b.z + a.w * b.w;
}

// One cooperative kernel, 512 blocks x 256 threads, 4 grid.sync()s.
// Phases: (1) x=hidden@W1^T  (2) fused scores+online-softmax ctx partials
//         (3) combine partials  (4) out GEMM split-K  (5) tanh + attn.T
__global__ __launch_bounds__(256) void mega(const float* __restrict__ hidden,
                                            const float* __restrict__ enc,
                                            const int* __restrict__ src_lens,
                                            const float* __restrict__ W1,
                                            const float* __restrict__ W2,
                                            float* __restrict__ out,
                                            float* __restrict__ x,
                                            float* __restrict__ scores,
                                            float* __restrict__ ctxp,
                                            float* __restrict__ m_part,
                                            float* __restrict__ l_part,
                                            float* __restrict__ Mb,
                                            float* __restrict__ Lb,
                                            float* __restrict__ ctx,
                                            float* __restrict__ outp) {
    cg::grid_group grid = cg::this_grid();
    int tid = threadIdx.x;
    int w = tid >> 6, lane = tid & 63;
    int blk = blockIdx.x;

    __shared__ float smem[8200];   // 32.8 KB union: ph2 lctx[4][256]f4 + lm/ll; ph4 tiles
    __shared__ int pfx[BB + 1];

    // ---- Phase 1: x = hidden @ W1^T (blocks 0..255; one wave per d-row) ----
    if (blk < 256) {
        int d = blk * 4 + w;
        const float4* wp = (const float4*)(W1 + (size_t)d * HH);
        float4 w0 = wp[lane], w1 = wp[lane + 64], w2v = wp[lane + 128], w3 = wp[lane + 192];
#pragma unroll 2
        for (int b = 0; b < BB; b += 2) {
            const float4* h0 = (const float4*)(hidden + (size_t)b * HH);
            const float4* h1 = (const float4*)(hidden + (size_t)(b + 1) * HH);
            float s0 = dot4(h0[lane], w0) + dot4(h0[lane + 64], w1) +
                       dot4(h0[lane + 128], w2v) + dot4(h0[lane + 192], w3);
            float s1 = dot4(h1[lane], w0) + dot4(h1[lane + 64], w1) +
                       dot4(h1[lane + 128], w2v) + dot4(h1[lane + 192], w3);
            s0 = wave_reduce_sum(s0);
            s1 = wave_reduce_sum(s1);
            if (lane == 0) { x[b * DD + d] = s0; x[(b + 1) * DD + d] = s1; }
        }
    }
    // every block computes the chunk prefix (cheap, input-only)
    if (tid == 0) {
        int a = 0;
        pfx[0] = 0;
#pragma unroll
        for (int b = 0; b < BB; ++b) {
            a += (src_lens[b] + 63) >> 6;
            pfx[b + 1] = a;
        }
    }

    grid.sync();

    // ---- Phase 2: fused scores + online-softmax ctx partials ----
    {
        int total = pfx[BB];
        float4* lctx = (float4*)smem;          // [4][256] float4 = 16 KB
        float* lm = smem + 4096 * 1 + 0;       // after 4096 floats? lctx uses 4096 floats*4B... 
        // NOTE: lctx = 4*256 float4 = 1024 float4 = 4096 floats. lm/ll after that.
        lm = smem + 4096;
        float* ll = smem + 4100;

        for (int chunk = blk; chunk < total; chunk += 512) {
            int b = 0;
            while (pfx[b + 1] <= chunk) ++b;  // uniform, <=32 iters
            int sp = chunk - pfx[b];
            int len = src_lens[b];
            int srow = sp * 64 + w * 16;

            float m = NEG_BIG, l = 0.f;
            float4 a0 = {0, 0, 0, 0}, a1 = {0, 0, 0, 0}, a2 = {0, 0, 0, 0}, a3 = {0, 0, 0, 0};

            if (srow < len) {
                const float4* xp = (const float4*)(x + (size_t)b * DD);
                float4 x0 = xp[lane], x1 = xp[lane + 64], x2 = xp[lane + 128], x3 = xp[lane + 192];
                int rend = min(16, len - srow);
                for (int r = 0; r < rend; ++r) {
                    int s = srow + r;
                    const float4* ep = (const float4*)(enc + ((size_t)b * SS + s) * DD);
                    float4 e0 = ep[lane], e1 = ep[lane + 64], e2 = ep[lane + 128], e3 = ep[lane + 192];
                    float part = dot4(e0, x0) + dot4(e1, x1) + dot4(e2, x2) + dot4(e3, x3);
                    part = wave_reduce_sum(part);
                    float v = part;
                    if (v == 0.0f) v = NEG_BIG;  // torch quirk: exact zeros -> -1e10
                    if (lane == 0) scores[b * SS + s] = v;
                    if (v > m) {  // wave-uniform
                        float sc = __expf(m - v);
                        m = v;
                        l *= sc;
                        a0.x *= sc; a0.y *= sc; a0.z *= sc; a0.w *= sc;
                        a1.x *= sc; a1.y *= sc; a1.z *= sc; a1.w *= sc;
                        a2.x *= sc; a2.y *= sc; a2.z *= sc; a2.w *= sc;
                        a3.x *= sc; a3.y *= sc; a3.z *= sc; a3.w *= sc;
                    }
                    float p = __expf(v - m);
                    l += p;
                    a0.x += p * e0.x; a0.y += p * e0.y; a0.z += p * e0.z; a0.w += p * e0.w;
                    a1.x += p * e1.x; a1.y += p * e1.y; a1.z += p * e1.z; a1.w += p * e1.w;
                    a2.x += p * e2.x; a2.y += p * e2.y; a2.z += p * e2.z; a2.w += p * e2.w;
                    a3.x += p * e3.x; a3.y += p * e3.y; a3.z += p * e3.z; a3.w += p * e3.w;
                }
            }

            lctx[w * 256 + lane] = a0;
            lctx[w * 256 + lane + 64] = a1;
            lctx[w * 256 + lane + 128] = a2;
            lctx[w * 256 + lane + 192] = a3;
            if (lane == 0) { lm[w] = m; ll[w] = l; }
            __syncthreads();

            {
                float M = fmaxf(fmaxf(lm[0], lm[1]), fmaxf(lm[2], lm[3]));
                float L = 0.f;
                float4 sum = {0, 0, 0, 0};
#pragma unroll
                for (int k = 0; k < 4; ++k) {
                    float sc = __expf(lm[k] - M);  // empty waves contribute 0
                    L += sc * ll[k];
                    float4 c = lctx[k * 256 + tid];
                    sum.x += sc * c.x; sum.y += sc * c.y; sum.z += sc * c.z; sum.w += sc * c.w;
                }
                int cc = ((tid >> 6) << 8) | ((tid & 63) << 2);
                *(float4*)(ctxp + ((size_t)(b * NSPLIT + sp)) * DD + cc) = sum;
                if (tid == 0) {
                    m_part[b * NSPLIT + sp] = M;
                    l_part[b * NSPLIT + sp] = L;
                }
            }
            __syncthreads();  // protect lctx reuse on next chunk
        }
    }

    grid.sync();

    // ---- Phase 3: combine partials -> ctx, Mb, Lb (blocks 0..127) ----
    if (blk < 128) {
        int b = blk >> 2;
        int col = (blk & 3) * 256 + tid;
        int nb = (src_lens[b] + 63) >> 6;
        float M = NEG_BIG;
        for (int k = 0; k < nb; ++k) M = fmaxf(M, m_part[b * NSPLIT + k]);
        float L = 0.f;
        float sum = 0.f;
        for (int k = 0; k < nb; ++k) {
            float sc = __expf(m_part[b * NSPLIT + k] - M);
            L += sc * l_part[b * NSPLIT + k];
            sum += sc * ctxp[((size_t)(b * NSPLIT + k)) * DD + col];
        }
        ctx[(size_t)b * DD + col] = sum / L;
        if (tid == 0 && (blk & 3) == 0) { Mb[b] = M; Lb[b] = L; }
    }

    grid.sync();

    // ---- Phase 4: out_part = cat([ctx,hidden]) @ W2^T, split-K (all 512 blocks) ----
    {
        int dt = blk & 31;
        int ks = blk >> 5;
        float* cat_s = smem;          // 32*128 floats = 16 KB
        float* w2_s = smem + 4096;    // 16 KB
        int b0 = tid & 15, b1 = b0 + 16;
        int dl0 = (tid >> 4) * 2, dl1 = dl0 + 1;
        float acc00 = 0.f, acc01 = 0.f, acc10 = 0.f, acc11 = 0.f;

        int j0 = ks * 128;
#pragma unroll
        for (int pass = 0; pass < 4; ++pass) {
            int r = pass * 8 + (tid >> 5);
            int jj4 = tid & 31;
            int j = j0 + jj4 * 4;
            const float* src = (j < 1024) ? (ctx + (size_t)r * 1024 + j)
                                          : (hidden + (size_t)r * 1024 + (j - 1024));
            float4 v = *(const float4*)src;
            *(float4*)(cat_s + r * 128 + ((jj4 ^ (r & 7)) << 2)) = v;
            int dg = dt * 32 + r;
            float4 wv = *(const float4*)(W2 + (size_t)dg * HD + j);
            *(float4*)(w2_s + r * 128 + ((jj4 ^ (r & 7)) << 2)) = wv;
        }
        __syncthreads();
#pragma unroll 4
        for (int jj4 = 0; jj4 < 32; ++jj4) {
            float4 cA = *(const float4*)(cat_s + b0 * 128 + ((jj4 ^ (b0 & 7)) << 2));
            float4 cB = *(const float4*)(cat_s + b1 * 128 + ((jj4 ^ (b1 & 7)) << 2));
            float4 wA = *(const float4*)(w2_s + dl0 * 128 + ((jj4 ^ (dl0 & 7)) << 2));
            float4 wB = *(const float4*)(w2_s + dl1 * 128 + ((jj4 ^ (dl1 & 7)) << 2));
            acc00 += dot4(cA, wA);
            acc01 += dot4(cA, wB);
            acc10 += dot4(cB, wA);
            acc11 += dot4(cB, wB);
        }
        float* op = outp + (size_t)ks * (BB * DD);
        op[b0 * 1024 + dt * 32 + dl0] = acc00;
        op[b0 * 1024 + dt * 32 + dl1] = acc01;
        op[b1 * 1024 + dt * 32 + dl0] = acc10;
        op[b1 * 1024 + dt * 32 + dl1] = acc11;
    }

    grid.sync();

    // ---- Phase 5: finalize (blocks 0..383): out=tanh(sum partials); attn.T ----
    if (blk < 384) {
        int i = blk * 256 + tid;
        if (i < BB * DD) {
            float s = 0.f;
#pragma unroll
            for (int k = 0; k < KSPLIT; ++k) s += outp[(size_t)k * (BB * DD) + i];
            out[i] = tanhf(s);
        } else {
            int j = i - BB * DD;           // attn.T index: j = s*B + b
            int b = j & 31, sIdx = j >> 5;
            float v = 0.0f;                // rows >= len: exp(-1e10 - M) == 0 exactly
            if (sIdx < src_lens[b]) v = __expf(scores[b * SS + sIdx] - Mb[b]) / Lb[b];
            out[i] = v;
        }
    }
}

extern "C" void kernel_launch(void* const* d_in, const int* in_sizes, int n_in,
                              void* d_out, int out_size, void* d_ws, size_t ws_size,
                              hipStream_t stream) {
    const float* hidden = (const float*)d_in[0];
    const float* enc = (const float*)d_in[1];
    const int* src_lens = (const int*)d_in[2];
    const float* W1 = (const float*)d_in[3];
    const float* W2 = (const float*)d_in[4];
    float* out = (float*)d_out;
    float* ws = (float*)d_ws;

    // ws layout (floats)
    float* x = ws;                       // 32768
    float* scores = ws + 32768;          // 65536
    float* ctxp = ws + 98304;            // 32*32*1024 = 1048576
    float* m_part = ws + 1146880;        // 1024
    float* l_part = ws + 1147904;        // 1024
    float* Mb = ws + 1148928;            // 32
    float* Lb = ws + 1148960;            // 32
    float* ctx = ws + 1148992;           // 32768
    float* outp = ws + 1181760;          // 16*32768 = 524288  (total ~6.8 MB)

    void* args[] = {(void*)&hidden, (void*)&enc, (void*)&src_lens, (void*)&W1, (void*)&W2,
                    (void*)&out, (void*)&x, (void*)&scores, (void*)&ctxp, (void*)&m_part,
                    (void*)&l_part, (void*)&Mb, (void*)&Lb, (void*)&ctx, (void*)&outp};
    hipLaunchCooperativeKernel((void*)mega, dim3(512), dim3(256), args, 0, stream);
}

// Round 6
// 70.386 us; speedup vs baseline: 3.8536x; 3.8536x over previous
//
#include <hip/hip_runtime.h>
#include <hip/hip_bf16.h>
#include <math.h>

// Problem constants
#define BB 32
#define SS 2048
#define HH 1024
#define DD 1024
#define HD 2048
#define NSPLIT 32   // 64-row chunks per batch (max)
#define KSPLIT 16   // K-splits for out GEMM
#define NEG_BIG -1e10f

__device__ __forceinline__ float wave_reduce_sum(float v) {
#pragma unroll
    for (int off = 32; off > 0; off >>= 1) v += __shfl_xor(v, off, 64);
    return v;
}

__device__ __forceinline__ float dot4(float4 a, float4 b) {
    return a.x * b.x + a.y * b.y + a.z * b.z + a.w * b.w;
}

// ---------------- K1: x = hidden @ W1^T  (B x D) ----------------
// grid 256, block 256 (4 waves). One wave per output row d; W1 read ONCE.
__global__ __launch_bounds__(256) void k1_gemv_x(const float* __restrict__ hidden,
                                                 const float* __restrict__ W1,
                                                 float* __restrict__ x) {
    __shared__ float4 hs[16 * 256];  // 64 KB: 16 batches of hidden
    int tid = threadIdx.x;
    int w = tid >> 6, lane = tid & 63;
    int d = blockIdx.x * 4 + w;
    const float4* wp = (const float4*)(W1 + (size_t)d * HH);
    float4 w0 = wp[lane], w1 = wp[lane + 64], w2 = wp[lane + 128], w3 = wp[lane + 192];
    const float4* hp = (const float4*)hidden;

    for (int half = 0; half < 2; ++half) {
        __syncthreads();
#pragma unroll
        for (int i = 0; i < 16; ++i) hs[i * 256 + tid] = hp[half * 4096 + i * 256 + tid];
        __syncthreads();
#pragma unroll 4
        for (int bl = 0; bl < 16; ++bl) {
            const float4* hb = hs + bl * 256;
            float s = dot4(hb[lane], w0) + dot4(hb[lane + 64], w1) +
                      dot4(hb[lane + 128], w2) + dot4(hb[lane + 192], w3);
            s = wave_reduce_sum(s);
            if (lane == 0) x[(half * 16 + bl) * DD + d] = s;
        }
    }
}

// ---------------- K2: fused scores + online-softmax ctx partials ----------------
// grid 512, block 512 (8 waves x 8 rows per 64-row chunk). Busy chunks
// flattened via in-block prefix, grid-strided for load balance.
__global__ __launch_bounds__(512) void k2_fused(const float* __restrict__ enc,
                                                const float* __restrict__ x,
                                                const int* __restrict__ src_lens,
                                                float* __restrict__ scores,
                                                float* __restrict__ ctxp,
                                                float* __restrict__ m_part,
                                                float* __restrict__ l_part) {
    int tid = threadIdx.x;
    int w = tid >> 6, lane = tid & 63;

    __shared__ int pfx[BB + 1];
    if (tid == 0) {
        int a = 0;
        pfx[0] = 0;
#pragma unroll
        for (int b = 0; b < BB; ++b) {
            a += (src_lens[b] + 63) >> 6;
            pfx[b + 1] = a;
        }
    }
    __shared__ float4 lctx[8][256];  // 32 KB
    __shared__ float lm[8], ll[8];
    __syncthreads();
    int total = pfx[BB];

    for (int chunk = blockIdx.x; chunk < total; chunk += gridDim.x) {
        int b = 0;
        while (pfx[b + 1] <= chunk) ++b;  // uniform, <=32 iters
        int sp = chunk - pfx[b];
        int len = src_lens[b];
        int srow = sp * 64 + w * 8;

        float m = NEG_BIG, l = 0.f;
        float4 a0 = {0, 0, 0, 0}, a1 = {0, 0, 0, 0}, a2 = {0, 0, 0, 0}, a3 = {0, 0, 0, 0};

        if (srow < len) {  // wave has at least one real row
            const float4* xp = (const float4*)(x + (size_t)b * DD);
            float4 x0 = xp[lane], x1 = xp[lane + 64], x2 = xp[lane + 128], x3 = xp[lane + 192];
            int rend = min(8, len - srow);
            for (int r = 0; r < rend; ++r) {
                int s = srow + r;
                const float4* ep = (const float4*)(enc + ((size_t)b * SS + s) * DD);
                float4 e0 = ep[lane], e1 = ep[lane + 64], e2 = ep[lane + 128], e3 = ep[lane + 192];
                float part = dot4(e0, x0) + dot4(e1, x1) + dot4(e2, x2) + dot4(e3, x3);
                part = wave_reduce_sum(part);  // butterfly: all lanes hold the sum
                float v = part;
                if (v == 0.0f) v = NEG_BIG;  // torch quirk: exact zeros -> -1e10
                if (lane == 0) scores[b * SS + s] = v;
                if (v > m) {  // wave-uniform
                    float sc = __expf(m - v);  // == 0.0 on first real row
                    m = v;
                    l *= sc;
                    a0.x *= sc; a0.y *= sc; a0.z *= sc; a0.w *= sc;
                    a1.x *= sc; a1.y *= sc; a1.z *= sc; a1.w *= sc;
                    a2.x *= sc; a2.y *= sc; a2.z *= sc; a2.w *= sc;
                    a3.x *= sc; a3.y *= sc; a3.z *= sc; a3.w *= sc;
                }
                float p = __expf(v - m);
                l += p;
                a0.x += p * e0.x; a0.y += p * e0.y; a0.z += p * e0.z; a0.w += p * e0.w;
                a1.x += p * e1.x; a1.y += p * e1.y; a1.z += p * e1.z; a1.w += p * e1.w;
                a2.x += p * e2.x; a2.y += p * e2.y; a2.z += p * e2.z; a2.w += p * e2.w;
                a3.x += p * e3.x; a3.y += p * e3.y; a3.z += p * e3.z; a3.w += p * e3.w;
            }
        }
        // rows >= len: untouched. K6 emits attn=0 for them (exp(-1e10-M)==0).

        lctx[w][lane] = a0;
        lctx[w][lane + 64] = a1;
        lctx[w][lane + 128] = a2;
        lctx[w][lane + 192] = a3;
        if (lane == 0) { lm[w] = m; ll[w] = l; }
        __syncthreads();

        if (tid < 256) {
            float M = lm[0];
#pragma unroll
            for (int k = 1; k < 8; ++k) M = fmaxf(M, lm[k]);
            float L = 0.f;
            float4 sum = {0, 0, 0, 0};
#pragma unroll
            for (int k = 0; k < 8; ++k) {
                float sc = __expf(lm[k] - M);  // empty waves contribute 0
                L += sc * ll[k];
                float4 c = lctx[k][tid];
                sum.x += sc * c.x; sum.y += sc * c.y; sum.z += sc * c.z; sum.w += sc * c.w;
            }
            // lctx[k][i] holds cols 256*(i/64) + 4*(i%64) .. +3
            int cc = ((tid >> 6) << 8) | ((tid & 63) << 2);
            *(float4*)(ctxp + ((size_t)(b * NSPLIT + sp)) * DD + cc) = sum;
            if (tid == 0) {
                m_part[b * NSPLIT + sp] = M;
                l_part[b * NSPLIT + sp] = L;
            }
        }
        __syncthreads();  // protect lctx reuse on next chunk
    }
}

// ---------------- K5': out GEMM reading ctxp directly (K3 folded in) ----------------
// grid 512 = 32 dtiles * 16 ksplits, block 256. Each block redundantly combines
// its 128-col ctx slice from ctxp using per-batch (M,L) computed from
// m_part/l_part (L2-served, ~4 us aggregate). LDS tiles XOR-swizzled.
__global__ __launch_bounds__(256) void k5_outgemm(const float* __restrict__ ctxp,
                                                  const float* __restrict__ m_part,
                                                  const float* __restrict__ l_part,
                                                  const int* __restrict__ src_lens,
                                                  const float* __restrict__ hidden,
                                                  const float* __restrict__ W2,
                                                  float* __restrict__ outp) {
    int dt = blockIdx.x & 31;
    int ks = blockIdx.x >> 5;
    int tid = threadIdx.x;
    __shared__ float cat_s[32 * 128];   // 16 KB
    __shared__ float w2_s[32 * 128];    // 16 KB
    __shared__ float scb[BB][NSPLIT];   // 4 KB: e^{m_c - M_b} / L_b
    __shared__ int nbs[BB];

    // per-batch M,L (redundant, tiny)
    if (tid < BB) {
        int b = tid;
        int nb = (src_lens[b] + 63) >> 6;
        nbs[b] = nb;
        float M = NEG_BIG;
        for (int c = 0; c < nb; ++c) M = fmaxf(M, m_part[b * NSPLIT + c]);
        float L = 0.f;
        for (int c = 0; c < nb; ++c) L += __expf(m_part[b * NSPLIT + c] - M) * l_part[b * NSPLIT + c];
        float rL = 1.0f / L;
        for (int c = 0; c < nb; ++c) scb[b][c] = __expf(m_part[b * NSPLIT + c] - M) * rL;
    }
    __syncthreads();

    int b0 = tid & 15, b1 = b0 + 16;
    int dl0 = (tid >> 4) * 2, dl1 = dl0 + 1;
    float acc00 = 0.f, acc01 = 0.f, acc10 = 0.f, acc11 = 0.f;

    int j0 = ks * 128;
#pragma unroll
    for (int pass = 0; pass < 4; ++pass) {
        int r = pass * 8 + (tid >> 5);
        int jj4 = tid & 31;
        int j = j0 + jj4 * 4;
        float4 v;
        if (j < 1024) {  // combine ctx slice from ctxp
            float4 s4 = {0, 0, 0, 0};
            int nb = nbs[r];
            for (int c = 0; c < nb; ++c) {
                float sc = scb[r][c];
                float4 p = *(const float4*)(ctxp + ((size_t)(r * NSPLIT + c)) * DD + j);
                s4.x += sc * p.x; s4.y += sc * p.y; s4.z += sc * p.z; s4.w += sc * p.w;
            }
            v = s4;
        } else {
            v = *(const float4*)(hidden + (size_t)r * 1024 + (j - 1024));
        }
        *(float4*)(cat_s + r * 128 + ((jj4 ^ (r & 7)) << 2)) = v;
        int dg = dt * 32 + r;
        float4 wv = *(const float4*)(W2 + (size_t)dg * HD + j);
        *(float4*)(w2_s + r * 128 + ((jj4 ^ (r & 7)) << 2)) = wv;
    }
    __syncthreads();
#pragma unroll 4
    for (int jj4 = 0; jj4 < 32; ++jj4) {
        float4 cA = *(const float4*)(cat_s + b0 * 128 + ((jj4 ^ (b0 & 7)) << 2));
        float4 cB = *(const float4*)(cat_s + b1 * 128 + ((jj4 ^ (b1 & 7)) << 2));
        float4 wA = *(const float4*)(w2_s + dl0 * 128 + ((jj4 ^ (dl0 & 7)) << 2));
        float4 wB = *(const float4*)(w2_s + dl1 * 128 + ((jj4 ^ (dl1 & 7)) << 2));
        acc00 += dot4(cA, wA);
        acc01 += dot4(cA, wB);
        acc10 += dot4(cB, wA);
        acc11 += dot4(cB, wB);
    }
    float* op = outp + (size_t)ks * (BB * DD);
    op[b0 * 1024 + dt * 32 + dl0] = acc00;
    op[b0 * 1024 + dt * 32 + dl1] = acc01;
    op[b1 * 1024 + dt * 32 + dl0] = acc10;
    op[b1 * 1024 + dt * 32 + dl1] = acc11;
}

// ---------------- K6': finalize: out = tanh(sum partials); attn.T ----------------
// grid 384, block 256: 98304 threads = 32768 (out) + 65536 (attn.T)
// Per-batch M,L recomputed in-block from m_part/l_part (no Mb/Lb dependency).
__global__ __launch_bounds__(256) void k6_final(const float* __restrict__ outp,
                                                const float* __restrict__ scores,
                                                const int* __restrict__ src_lens,
                                                const float* __restrict__ m_part,
                                                const float* __restrict__ l_part,
                                                float* __restrict__ out) {
    __shared__ float Msh[BB], rLsh[BB];
    int tid = threadIdx.x;
    if (blockIdx.x >= 128 && tid < BB) {  // only attn blocks need M,L
        int b = tid;
        int nb = (src_lens[b] + 63) >> 6;
        float M = NEG_BIG;
        for (int c = 0; c < nb; ++c) M = fmaxf(M, m_part[b * NSPLIT + c]);
        float L = 0.f;
        for (int c = 0; c < nb; ++c) L += __expf(m_part[b * NSPLIT + c] - M) * l_part[b * NSPLIT + c];
        Msh[b] = M;
        rLsh[b] = 1.0f / L;
    }
    __syncthreads();

    int i = blockIdx.x * 256 + tid;
    if (i < BB * DD) {
        float s = 0.f;
#pragma unroll
        for (int k = 0; k < KSPLIT; ++k) s += outp[(size_t)k * (BB * DD) + i];
        out[i] = tanhf(s);
    } else {
        int j = i - BB * DD;           // attn.T index: j = s*B + b
        int b = j & 31, sIdx = j >> 5;
        float v = 0.0f;                // rows >= len: exp(-1e10 - M) == 0 exactly
        if (sIdx < src_lens[b]) v = __expf(scores[b * SS + sIdx] - Msh[b]) * rLsh[b];
        out[i] = v;
    }
}

extern "C" void kernel_launch(void* const* d_in, const int* in_sizes, int n_in,
                              void* d_out, int out_size, void* d_ws, size_t ws_size,
                              hipStream_t stream) {
    const float* hidden = (const float*)d_in[0];
    const float* enc = (const float*)d_in[1];
    const int* src_lens = (const int*)d_in[2];
    const float* W1 = (const float*)d_in[3];
    const float* W2 = (const float*)d_in[4];
    float* out = (float*)d_out;
    float* ws = (float*)d_ws;

    // ws layout (floats)
    float* x = ws;                       // 32768
    float* scores = ws + 32768;          // 65536
    float* ctxp = ws + 98304;            // 32*32*1024 = 1048576
    float* m_part = ws + 1146880;        // 1024
    float* l_part = ws + 1147904;        // 1024
    float* outp = ws + 1148928;          // 16*32768 = 524288  (total ~6.7 MB)

    k1_gemv_x<<<256, 256, 0, stream>>>(hidden, W1, x);
    k2_fused<<<512, 512, 0, stream>>>(enc, x, src_lens, scores, ctxp, m_part, l_part);
    k5_outgemm<<<512, 256, 0, stream>>>(ctxp, m_part, l_part, src_lens, hidden, W2, outp);
    k6_final<<<384, 256, 0, stream>>>(outp, scores, src_lens, m_part, l_part, out);
}

// Round 7
// 69.329 us; speedup vs baseline: 3.9124x; 1.0152x over previous
//
#include <hip/hip_runtime.h>
#include <hip/hip_bf16.h>
#include <math.h>

// Problem constants
#define BB 32
#define SS 2048
#define HH 1024
#define DD 1024
#define HD 2048
#define NSPLIT 64   // 32-row chunks per batch (max)
#define KSPLIT 16   // K-splits for out GEMM
#define NEG_BIG -1e10f

__device__ __forceinline__ float wave_reduce_sum(float v) {
#pragma unroll
    for (int off = 32; off > 0; off >>= 1) v += __shfl_xor(v, off, 64);
    return v;
}

__device__ __forceinline__ float dot4(float4 a, float4 b) {
    return a.x * b.x + a.y * b.y + a.z * b.z + a.w * b.w;
}

// ---------------- K1: x = hidden @ W1^T  (B x D) ----------------
__global__ __launch_bounds__(256) void k1_gemv_x(const float* __restrict__ hidden,
                                                 const float* __restrict__ W1,
                                                 float* __restrict__ x) {
    __shared__ float4 hs[16 * 256];  // 64 KB: 16 batches of hidden
    int tid = threadIdx.x;
    int w = tid >> 6, lane = tid & 63;
    int d = blockIdx.x * 4 + w;
    const float4* wp = (const float4*)(W1 + (size_t)d * HH);
    float4 w0 = wp[lane], w1 = wp[lane + 64], w2 = wp[lane + 128], w3 = wp[lane + 192];
    const float4* hp = (const float4*)hidden;

    for (int half = 0; half < 2; ++half) {
        __syncthreads();
#pragma unroll
        for (int i = 0; i < 16; ++i) hs[i * 256 + tid] = hp[half * 4096 + i * 256 + tid];
        __syncthreads();
#pragma unroll 4
        for (int bl = 0; bl < 16; ++bl) {
            const float4* hb = hs + bl * 256;
            float s = dot4(hb[lane], w0) + dot4(hb[lane + 64], w1) +
                      dot4(hb[lane + 128], w2) + dot4(hb[lane + 192], w3);
            s = wave_reduce_sum(s);
            if (lane == 0) x[(half * 16 + bl) * DD + d] = s;
        }
    }
}

// ---------------- K2: fused scores + online-softmax ctx partials ----------------
// grid 1024, block 256 (4 waves x 8 rows per 32-row chunk). Pair-unrolled rows:
// two rows' loads in flight per wave (8 KB MLP), butterflies interleaved.
__global__ __launch_bounds__(256) void k2_fused(const float* __restrict__ enc,
                                                const float* __restrict__ x,
                                                const int* __restrict__ src_lens,
                                                float* __restrict__ scores,
                                                float* __restrict__ ctxp,
                                                float* __restrict__ m_part,
                                                float* __restrict__ l_part) {
    int tid = threadIdx.x;
    int w = tid >> 6, lane = tid & 63;

    __shared__ int pfx[BB + 1];
    if (tid == 0) {
        int a = 0;
        pfx[0] = 0;
#pragma unroll
        for (int b = 0; b < BB; ++b) {
            a += (src_lens[b] + 31) >> 5;
            pfx[b + 1] = a;
        }
    }
    __shared__ float4 lctx[4][256];  // 16 KB
    __shared__ float lm[4], ll[4];
    __syncthreads();
    int total = pfx[BB];

    for (int chunk = blockIdx.x; chunk < total; chunk += gridDim.x) {
        int b = 0;
        while (pfx[b + 1] <= chunk) ++b;  // uniform, <=32 iters
        int sp = chunk - pfx[b];
        int len = src_lens[b];
        int srow = sp * 32 + w * 8;

        float m = NEG_BIG, l = 0.f;
        float4 a0 = {0, 0, 0, 0}, a1 = {0, 0, 0, 0}, a2 = {0, 0, 0, 0}, a3 = {0, 0, 0, 0};

        if (srow < len) {
            const float4* xp = (const float4*)(x + (size_t)b * DD);
            float4 x0 = xp[lane], x1 = xp[lane + 64], x2 = xp[lane + 128], x3 = xp[lane + 192];
            int rend = min(8, len - srow);
            const float* erow = enc + ((size_t)b * SS + srow) * DD;
            int r = 0;
            for (; r + 2 <= rend; r += 2) {
                const float4* ep = (const float4*)(erow + (size_t)r * DD);
                const float4* fp = (const float4*)(erow + (size_t)(r + 1) * DD);
                float4 e0 = ep[lane], e1 = ep[lane + 64], e2 = ep[lane + 128], e3 = ep[lane + 192];
                float4 f0 = fp[lane], f1 = fp[lane + 64], f2 = fp[lane + 128], f3 = fp[lane + 192];
                float p0 = dot4(e0, x0) + dot4(e1, x1) + dot4(e2, x2) + dot4(e3, x3);
                float p1 = dot4(f0, x0) + dot4(f1, x1) + dot4(f2, x2) + dot4(f3, x3);
#pragma unroll
                for (int off = 32; off > 0; off >>= 1) {  // interleaved butterflies
                    p0 += __shfl_xor(p0, off, 64);
                    p1 += __shfl_xor(p1, off, 64);
                }
                float v0 = (p0 == 0.0f) ? NEG_BIG : p0;  // torch quirk
                float v1 = (p1 == 0.0f) ? NEG_BIG : p1;
                if (lane == 0) {
                    scores[b * SS + srow + r] = v0;
                    scores[b * SS + srow + r + 1] = v1;
                }
                if (v0 > m) {  // wave-uniform
                    float sc = __expf(m - v0);
                    m = v0; l *= sc;
                    a0.x *= sc; a0.y *= sc; a0.z *= sc; a0.w *= sc;
                    a1.x *= sc; a1.y *= sc; a1.z *= sc; a1.w *= sc;
                    a2.x *= sc; a2.y *= sc; a2.z *= sc; a2.w *= sc;
                    a3.x *= sc; a3.y *= sc; a3.z *= sc; a3.w *= sc;
                }
                float q0 = __expf(v0 - m);
                l += q0;
                a0.x += q0 * e0.x; a0.y += q0 * e0.y; a0.z += q0 * e0.z; a0.w += q0 * e0.w;
                a1.x += q0 * e1.x; a1.y += q0 * e1.y; a1.z += q0 * e1.z; a1.w += q0 * e1.w;
                a2.x += q0 * e2.x; a2.y += q0 * e2.y; a2.z += q0 * e2.z; a2.w += q0 * e2.w;
                a3.x += q0 * e3.x; a3.y += q0 * e3.y; a3.z += q0 * e3.z; a3.w += q0 * e3.w;
                if (v1 > m) {
                    float sc = __expf(m - v1);
                    m = v1; l *= sc;
                    a0.x *= sc; a0.y *= sc; a0.z *= sc; a0.w *= sc;
                    a1.x *= sc; a1.y *= sc; a1.z *= sc; a1.w *= sc;
                    a2.x *= sc; a2.y *= sc; a2.z *= sc; a2.w *= sc;
                    a3.x *= sc; a3.y *= sc; a3.z *= sc; a3.w *= sc;
                }
                float q1 = __expf(v1 - m);
                l += q1;
                a0.x += q1 * f0.x; a0.y += q1 * f0.y; a0.z += q1 * f0.z; a0.w += q1 * f0.w;
                a1.x += q1 * f1.x; a1.y += q1 * f1.y; a1.z += q1 * f1.z; a1.w += q1 * f1.w;
                a2.x += q1 * f2.x; a2.y += q1 * f2.y; a2.z += q1 * f2.z; a2.w += q1 * f2.w;
                a3.x += q1 * f3.x; a3.y += q1 * f3.y; a3.z += q1 * f3.z; a3.w += q1 * f3.w;
            }
            if (r < rend) {  // odd tail
                const float4* ep = (const float4*)(erow + (size_t)r * DD);
                float4 e0 = ep[lane], e1 = ep[lane + 64], e2 = ep[lane + 128], e3 = ep[lane + 192];
                float p0 = dot4(e0, x0) + dot4(e1, x1) + dot4(e2, x2) + dot4(e3, x3);
                p0 = wave_reduce_sum(p0);
                float v0 = (p0 == 0.0f) ? NEG_BIG : p0;
                if (lane == 0) scores[b * SS + srow + r] = v0;
                if (v0 > m) {
                    float sc = __expf(m - v0);
                    m = v0; l *= sc;
                    a0.x *= sc; a0.y *= sc; a0.z *= sc; a0.w *= sc;
                    a1.x *= sc; a1.y *= sc; a1.z *= sc; a1.w *= sc;
                    a2.x *= sc; a2.y *= sc; a2.z *= sc; a2.w *= sc;
                    a3.x *= sc; a3.y *= sc; a3.z *= sc; a3.w *= sc;
                }
                float q0 = __expf(v0 - m);
                l += q0;
                a0.x += q0 * e0.x; a0.y += q0 * e0.y; a0.z += q0 * e0.z; a0.w += q0 * e0.w;
                a1.x += q0 * e1.x; a1.y += q0 * e1.y; a1.z += q0 * e1.z; a1.w += q0 * e1.w;
                a2.x += q0 * e2.x; a2.y += q0 * e2.y; a2.z += q0 * e2.z; a2.w += q0 * e2.w;
                a3.x += q0 * e3.x; a3.y += q0 * e3.y; a3.z += q0 * e3.z; a3.w += q0 * e3.w;
            }
        }
        // rows >= len: untouched; downstream emits attn=0 (exp(-1e10-M)==0).

        lctx[w][lane] = a0;
        lctx[w][lane + 64] = a1;
        lctx[w][lane + 128] = a2;
        lctx[w][lane + 192] = a3;
        if (lane == 0) { lm[w] = m; ll[w] = l; }
        __syncthreads();

        {
            float M = fmaxf(fmaxf(lm[0], lm[1]), fmaxf(lm[2], lm[3]));
            float L = 0.f;
            float4 sum = {0, 0, 0, 0};
#pragma unroll
            for (int k = 0; k < 4; ++k) {
                float sc = __expf(lm[k] - M);  // empty waves contribute 0
                L += sc * ll[k];
                float4 c = lctx[k][tid];
                sum.x += sc * c.x; sum.y += sc * c.y; sum.z += sc * c.z; sum.w += sc * c.w;
            }
            int cc = ((tid >> 6) << 8) | ((tid & 63) << 2);
            *(float4*)(ctxp + ((size_t)(b * NSPLIT + sp)) * DD + cc) = sum;
            if (tid == 0) {
                m_part[b * NSPLIT + sp] = M;
                l_part[b * NSPLIT + sp] = L;
            }
        }
        __syncthreads();  // protect lctx reuse on next chunk
    }
}

// ---------------- K3: combine busy partials -> ctx, Mb, Lb ----------------
// grid 128 = B*4 (one block per (b, 256-col tile)), block 256.
__global__ __launch_bounds__(256) void k3_combine(const float* __restrict__ ctxp,
                                                  const float* __restrict__ m_part,
                                                  const float* __restrict__ l_part,
                                                  const int* __restrict__ src_lens,
                                                  float* __restrict__ ctx,
                                                  float* __restrict__ Mb,
                                                  float* __restrict__ Lb) {
    int b = blockIdx.x >> 2;
    int col = (blockIdx.x & 3) * 256 + threadIdx.x;
    int nb = (src_lens[b] + 31) >> 5;  // busy chunks for this batch
    float M = NEG_BIG;
    for (int k = 0; k < nb; ++k) M = fmaxf(M, m_part[b * NSPLIT + k]);
    float L = 0.f;
    float sum = 0.f;
    for (int k = 0; k < nb; ++k) {
        float sc = __expf(m_part[b * NSPLIT + k] - M);
        L += sc * l_part[b * NSPLIT + k];
        sum += sc * ctxp[((size_t)(b * NSPLIT + k)) * DD + col];
    }
    ctx[(size_t)b * DD + col] = sum / L;
    if (threadIdx.x == 0 && (blockIdx.x & 3) == 0) { Mb[b] = M; Lb[b] = L; }
}

// ---------------- K5: out_part = cat([ctx,hidden]) @ W2^T (split-K) ----------------
// grid 512 = 32 dtiles * 16 ksplits, block 256. LDS tiles XOR-swizzled.
__global__ __launch_bounds__(256) void k5_outgemm(const float* __restrict__ ctx,
                                                  const float* __restrict__ hidden,
                                                  const float* __restrict__ W2,
                                                  float* __restrict__ outp) {
    int dt = blockIdx.x & 31;
    int ks = blockIdx.x >> 5;
    int tid = threadIdx.x;
    __shared__ float cat_s[32 * 128];
    __shared__ float w2_s[32 * 128];
    int b0 = tid & 15, b1 = b0 + 16;
    int dl0 = (tid >> 4) * 2, dl1 = dl0 + 1;
    float acc00 = 0.f, acc01 = 0.f, acc10 = 0.f, acc11 = 0.f;

    int j0 = ks * 128;
#pragma unroll
    for (int pass = 0; pass < 4; ++pass) {
        int r = pass * 8 + (tid >> 5);
        int jj4 = tid & 31;
        int j = j0 + jj4 * 4;
        const float* src = (j < 1024) ? (ctx + (size_t)r * 1024 + j)
                                      : (hidden + (size_t)r * 1024 + (j - 1024));
        float4 v = *(const float4*)src;
        *(float4*)(cat_s + r * 128 + ((jj4 ^ (r & 7)) << 2)) = v;
        int dg = dt * 32 + r;
        float4 wv = *(const float4*)(W2 + (size_t)dg * HD + j);
        *(float4*)(w2_s + r * 128 + ((jj4 ^ (r & 7)) << 2)) = wv;
    }
    __syncthreads();
#pragma unroll 4
    for (int jj4 = 0; jj4 < 32; ++jj4) {
        float4 cA = *(const float4*)(cat_s + b0 * 128 + ((jj4 ^ (b0 & 7)) << 2));
        float4 cB = *(const float4*)(cat_s + b1 * 128 + ((jj4 ^ (b1 & 7)) << 2));
        float4 wA = *(const float4*)(w2_s + dl0 * 128 + ((jj4 ^ (dl0 & 7)) << 2));
        float4 wB = *(const float4*)(w2_s + dl1 * 128 + ((jj4 ^ (dl1 & 7)) << 2));
        acc00 += dot4(cA, wA);
        acc01 += dot4(cA, wB);
        acc10 += dot4(cB, wA);
        acc11 += dot4(cB, wB);
    }
    float* op = outp + (size_t)ks * (BB * DD);
    op[b0 * 1024 + dt * 32 + dl0] = acc00;
    op[b0 * 1024 + dt * 32 + dl1] = acc01;
    op[b1 * 1024 + dt * 32 + dl0] = acc10;
    op[b1 * 1024 + dt * 32 + dl1] = acc11;
}

// ---------------- K6: finalize: out = tanh(sum partials); attn.T ----------------
__global__ __launch_bounds__(256) void k6_final(const float* __restrict__ outp,
                                                const float* __restrict__ scores,
                                                const int* __restrict__ src_lens,
                                                const float* __restrict__ Mb,
                                                const float* __restrict__ Lb,
                                                float* __restrict__ out) {
    int i = blockIdx.x * 256 + threadIdx.x;
    if (i < BB * DD) {
        float s = 0.f;
#pragma unroll
        for (int k = 0; k < KSPLIT; ++k) s += outp[(size_t)k * (BB * DD) + i];
        out[i] = tanhf(s);
    } else {
        int j = i - BB * DD;           // attn.T index: j = s*B + b
        int b = j & 31, sIdx = j >> 5;
        float v = 0.0f;                // rows >= len: exp(-1e10 - M) == 0 exactly
        if (sIdx < src_lens[b]) v = __expf(scores[b * SS + sIdx] - Mb[b]) / Lb[b];
        out[i] = v;
    }
}

extern "C" void kernel_launch(void* const* d_in, const int* in_sizes, int n_in,
                              void* d_out, int out_size, void* d_ws, size_t ws_size,
                              hipStream_t stream) {
    const float* hidden = (const float*)d_in[0];
    const float* enc = (const float*)d_in[1];
    const int* src_lens = (const int*)d_in[2];
    const float* W1 = (const float*)d_in[3];
    const float* W2 = (const float*)d_in[4];
    float* out = (float*)d_out;
    float* ws = (float*)d_ws;

    // ws layout (floats)
    float* x = ws;                       // 32768
    float* scores = ws + 32768;          // 65536
    float* ctxp = ws + 98304;            // 32*64*1024 = 2097152
    float* m_part = ws + 2195456;        // 2048
    float* l_part = ws + 2197504;        // 2048
    float* Mb = ws + 2199552;            // 32
    float* Lb = ws + 2199584;            // 32
    float* ctx = ws + 2199616;           // 32768
    float* outp = ws + 2232384;          // 16*32768 = 524288  (total ~11 MB)

    k1_gemv_x<<<256, 256, 0, stream>>>(hidden, W1, x);
    k2_fused<<<1024, 256, 0, stream>>>(enc, x, src_lens, scores, ctxp, m_part, l_part);
    k3_combine<<<128, 256, 0, stream>>>(ctxp, m_part, l_part, src_lens, ctx, Mb, Lb);
    k5_outgemm<<<512, 256, 0, stream>>>(ctx, hidden, W2, outp);
    k6_final<<<384, 256, 0, stream>>>(outp, scores, src_lens, Mb, Lb, out);
}

// Round 8
// 57.538 us; speedup vs baseline: 4.7141x; 1.2049x over previous
//
#include <hip/hip_runtime.h>
#include <hip/hip_bf16.h>
#include <math.h>

// Problem constants
#define BB 32
#define SS 2048
#define HH 1024
#define DD 1024
#define HD 2048
#define NSPLIT 32   // 64-row chunks per batch (max)
#define KSPLIT 16   // K-splits for out GEMM
#define NEG_BIG -1e10f

__device__ __forceinline__ float wave_reduce_sum(float v) {
#pragma unroll
    for (int off = 32; off > 0; off >>= 1) v += __shfl_xor(v, off, 64);
    return v;
}

__device__ __forceinline__ float dot4(float4 a, float4 b) {
    return a.x * b.x + a.y * b.y + a.z * b.z + a.w * b.w;
}

// ---------------- K1: x = hidden @ W1^T  (B x D) ----------------
// grid 256, block 256. One wave per output row d; W1 read ONCE.
// Batches processed in PAIRS with interleaved butterflies (1 wave/SIMD here,
// so serial shuffle latency is otherwise fully exposed).
__global__ __launch_bounds__(256) void k1_gemv_x(const float* __restrict__ hidden,
                                                 const float* __restrict__ W1,
                                                 float* __restrict__ x) {
    __shared__ float4 hs[16 * 256];  // 64 KB: 16 batches of hidden
    int tid = threadIdx.x;
    int w = tid >> 6, lane = tid & 63;
    int d = blockIdx.x * 4 + w;
    const float4* wp = (const float4*)(W1 + (size_t)d * HH);
    float4 w0 = wp[lane], w1 = wp[lane + 64], w2 = wp[lane + 128], w3 = wp[lane + 192];
    const float4* hp = (const float4*)hidden;

    for (int half = 0; half < 2; ++half) {
        __syncthreads();
#pragma unroll
        for (int i = 0; i < 16; ++i) hs[i * 256 + tid] = hp[half * 4096 + i * 256 + tid];
        __syncthreads();
#pragma unroll
        for (int bl = 0; bl < 16; bl += 2) {
            const float4* hb0 = hs + bl * 256;
            const float4* hb1 = hs + (bl + 1) * 256;
            float s0 = dot4(hb0[lane], w0) + dot4(hb0[lane + 64], w1) +
                       dot4(hb0[lane + 128], w2) + dot4(hb0[lane + 192], w3);
            float s1 = dot4(hb1[lane], w0) + dot4(hb1[lane + 64], w1) +
                       dot4(hb1[lane + 128], w2) + dot4(hb1[lane + 192], w3);
#pragma unroll
            for (int off = 32; off > 0; off >>= 1) {
                s0 += __shfl_xor(s0, off, 64);
                s1 += __shfl_xor(s1, off, 64);
            }
            if (lane == 0) {
                x[(half * 16 + bl) * DD + d] = s0;
                x[(half * 16 + bl + 1) * DD + d] = s1;
            }
        }
    }
}

// ---------------- K2: fused scores + online-softmax ctx partials ----------------
// grid 512, block 512 (8 waves x 8 rows per 64-row chunk) — exact R4 shape.
// ONLY the inner loop changed: 4-row groups, 16 loads in flight, 4-way
// interleaved butterflies, branchless one-rescale-per-group.
__global__ __launch_bounds__(512) void k2_fused(const float* __restrict__ enc,
                                                const float* __restrict__ x,
                                                const int* __restrict__ src_lens,
                                                float* __restrict__ scores,
                                                float* __restrict__ ctxp,
                                                float* __restrict__ m_part,
                                                float* __restrict__ l_part) {
    int tid = threadIdx.x;
    int w = tid >> 6, lane = tid & 63;

    __shared__ int pfx[BB + 1];
    if (tid == 0) {
        int a = 0;
        pfx[0] = 0;
#pragma unroll
        for (int b = 0; b < BB; ++b) {
            a += (src_lens[b] + 63) >> 6;
            pfx[b + 1] = a;
        }
    }
    __shared__ float4 lctx[8][256];  // 32 KB
    __shared__ float lm[8], ll[8];
    __syncthreads();
    int total = pfx[BB];

    for (int chunk = blockIdx.x; chunk < total; chunk += gridDim.x) {
        int b = 0;
        while (pfx[b + 1] <= chunk) ++b;  // uniform, <=32 iters
        int sp = chunk - pfx[b];
        int len = src_lens[b];
        int srow = sp * 64 + w * 8;

        float m = NEG_BIG, l = 0.f;
        float4 a0 = {0, 0, 0, 0}, a1 = {0, 0, 0, 0}, a2 = {0, 0, 0, 0}, a3 = {0, 0, 0, 0};

        if (srow < len) {
            const float4* xp = (const float4*)(x + (size_t)b * DD);
            float4 x0 = xp[lane], x1 = xp[lane + 64], x2 = xp[lane + 128], x3 = xp[lane + 192];
            int rend = min(8, len - srow);
            const float* erow = enc + ((size_t)b * SS + srow) * DD;
            int r = 0;
            for (; r + 4 <= rend; r += 4) {
                const float4* pr0 = (const float4*)(erow + (size_t)(r + 0) * DD);
                const float4* pr1 = (const float4*)(erow + (size_t)(r + 1) * DD);
                const float4* pr2 = (const float4*)(erow + (size_t)(r + 2) * DD);
                const float4* pr3 = (const float4*)(erow + (size_t)(r + 3) * DD);
                float4 e00 = pr0[lane], e01 = pr0[lane + 64], e02 = pr0[lane + 128], e03 = pr0[lane + 192];
                float4 e10 = pr1[lane], e11 = pr1[lane + 64], e12 = pr1[lane + 128], e13 = pr1[lane + 192];
                float4 e20 = pr2[lane], e21 = pr2[lane + 64], e22 = pr2[lane + 128], e23 = pr2[lane + 192];
                float4 e30 = pr3[lane], e31 = pr3[lane + 64], e32 = pr3[lane + 128], e33 = pr3[lane + 192];
                float p0 = dot4(e00, x0) + dot4(e01, x1) + dot4(e02, x2) + dot4(e03, x3);
                float p1 = dot4(e10, x0) + dot4(e11, x1) + dot4(e12, x2) + dot4(e13, x3);
                float p2 = dot4(e20, x0) + dot4(e21, x1) + dot4(e22, x2) + dot4(e23, x3);
                float p3 = dot4(e30, x0) + dot4(e31, x1) + dot4(e32, x2) + dot4(e33, x3);
#pragma unroll
                for (int off = 32; off > 0; off >>= 1) {  // 4-way interleaved butterflies
                    p0 += __shfl_xor(p0, off, 64);
                    p1 += __shfl_xor(p1, off, 64);
                    p2 += __shfl_xor(p2, off, 64);
                    p3 += __shfl_xor(p3, off, 64);
                }
                float v0 = (p0 == 0.0f) ? NEG_BIG : p0;  // torch quirk
                float v1 = (p1 == 0.0f) ? NEG_BIG : p1;
                float v2 = (p2 == 0.0f) ? NEG_BIG : p2;
                float v3 = (p3 == 0.0f) ? NEG_BIG : p3;
                if (lane == 0) {
                    scores[b * SS + srow + r + 0] = v0;
                    scores[b * SS + srow + r + 1] = v1;
                    scores[b * SS + srow + r + 2] = v2;
                    scores[b * SS + srow + r + 3] = v3;
                }
                float mm = fmaxf(m, fmaxf(fmaxf(v0, v1), fmaxf(v2, v3)));
                float sc = __expf(m - mm);  // == 1.0 when mm == m
                m = mm;
                l *= sc;
                a0.x *= sc; a0.y *= sc; a0.z *= sc; a0.w *= sc;
                a1.x *= sc; a1.y *= sc; a1.z *= sc; a1.w *= sc;
                a2.x *= sc; a2.y *= sc; a2.z *= sc; a2.w *= sc;
                a3.x *= sc; a3.y *= sc; a3.z *= sc; a3.w *= sc;
                float q0 = __expf(v0 - mm), q1 = __expf(v1 - mm);
                float q2 = __expf(v2 - mm), q3 = __expf(v3 - mm);
                l += q0 + q1 + q2 + q3;
                a0.x += q0 * e00.x + q1 * e10.x + q2 * e20.x + q3 * e30.x;
                a0.y += q0 * e00.y + q1 * e10.y + q2 * e20.y + q3 * e30.y;
                a0.z += q0 * e00.z + q1 * e10.z + q2 * e20.z + q3 * e30.z;
                a0.w += q0 * e00.w + q1 * e10.w + q2 * e20.w + q3 * e30.w;
                a1.x += q0 * e01.x + q1 * e11.x + q2 * e21.x + q3 * e31.x;
                a1.y += q0 * e01.y + q1 * e11.y + q2 * e21.y + q3 * e31.y;
                a1.z += q0 * e01.z + q1 * e11.z + q2 * e21.z + q3 * e31.z;
                a1.w += q0 * e01.w + q1 * e11.w + q2 * e21.w + q3 * e31.w;
                a2.x += q0 * e02.x + q1 * e12.x + q2 * e22.x + q3 * e32.x;
                a2.y += q0 * e02.y + q1 * e12.y + q2 * e22.y + q3 * e32.y;
                a2.z += q0 * e02.z + q1 * e12.z + q2 * e22.z + q3 * e32.z;
                a2.w += q0 * e02.w + q1 * e12.w + q2 * e22.w + q3 * e32.w;
                a3.x += q0 * e03.x + q1 * e13.x + q2 * e23.x + q3 * e33.x;
                a3.y += q0 * e03.y + q1 * e13.y + q2 * e23.y + q3 * e33.y;
                a3.z += q0 * e03.z + q1 * e13.z + q2 * e23.z + q3 * e33.z;
                a3.w += q0 * e03.w + q1 * e13.w + q2 * e23.w + q3 * e33.w;
            }
            for (; r < rend; ++r) {  // tail (0..3 rows)
                const float4* ep = (const float4*)(erow + (size_t)r * DD);
                float4 e0 = ep[lane], e1 = ep[lane + 64], e2 = ep[lane + 128], e3 = ep[lane + 192];
                float p0 = dot4(e0, x0) + dot4(e1, x1) + dot4(e2, x2) + dot4(e3, x3);
                p0 = wave_reduce_sum(p0);
                float v0 = (p0 == 0.0f) ? NEG_BIG : p0;
                if (lane == 0) scores[b * SS + srow + r] = v0;
                float mm = fmaxf(m, v0);
                float sc = __expf(m - mm);
                m = mm;
                l *= sc;
                a0.x *= sc; a0.y *= sc; a0.z *= sc; a0.w *= sc;
                a1.x *= sc; a1.y *= sc; a1.z *= sc; a1.w *= sc;
                a2.x *= sc; a2.y *= sc; a2.z *= sc; a2.w *= sc;
                a3.x *= sc; a3.y *= sc; a3.z *= sc; a3.w *= sc;
                float q0 = __expf(v0 - mm);
                l += q0;
                a0.x += q0 * e0.x; a0.y += q0 * e0.y; a0.z += q0 * e0.z; a0.w += q0 * e0.w;
                a1.x += q0 * e1.x; a1.y += q0 * e1.y; a1.z += q0 * e1.z; a1.w += q0 * e1.w;
                a2.x += q0 * e2.x; a2.y += q0 * e2.y; a2.z += q0 * e2.z; a2.w += q0 * e2.w;
                a3.x += q0 * e3.x; a3.y += q0 * e3.y; a3.z += q0 * e3.z; a3.w += q0 * e3.w;
            }
        }
        // rows >= len: untouched; downstream emits attn=0 (exp(-1e10-M)==0).

        lctx[w][lane] = a0;
        lctx[w][lane + 64] = a1;
        lctx[w][lane + 128] = a2;
        lctx[w][lane + 192] = a3;
        if (lane == 0) { lm[w] = m; ll[w] = l; }
        __syncthreads();

        if (tid < 256) {
            float M = lm[0];
#pragma unroll
            for (int k = 1; k < 8; ++k) M = fmaxf(M, lm[k]);
            float L = 0.f;
            float4 sum = {0, 0, 0, 0};
#pragma unroll
            for (int k = 0; k < 8; ++k) {
                float sc = __expf(lm[k] - M);  // empty waves contribute 0
                L += sc * ll[k];
                float4 c = lctx[k][tid];
                sum.x += sc * c.x; sum.y += sc * c.y; sum.z += sc * c.z; sum.w += sc * c.w;
            }
            int cc = ((tid >> 6) << 8) | ((tid & 63) << 2);
            *(float4*)(ctxp + ((size_t)(b * NSPLIT + sp)) * DD + cc) = sum;
            if (tid == 0) {
                m_part[b * NSPLIT + sp] = M;
                l_part[b * NSPLIT + sp] = L;
            }
        }
        __syncthreads();  // protect lctx reuse on next chunk
    }
}

// ---------------- K3: combine busy partials -> ctx, Mb, Lb ----------------
__global__ __launch_bounds__(256) void k3_combine(const float* __restrict__ ctxp,
                                                  const float* __restrict__ m_part,
                                                  const float* __restrict__ l_part,
                                                  const int* __restrict__ src_lens,
                                                  float* __restrict__ ctx,
                                                  float* __restrict__ Mb,
                                                  float* __restrict__ Lb) {
    int b = blockIdx.x >> 2;
    int col = (blockIdx.x & 3) * 256 + threadIdx.x;
    int nb = (src_lens[b] + 63) >> 6;  // busy chunks for this batch
    float M = NEG_BIG;
    for (int k = 0; k < nb; ++k) M = fmaxf(M, m_part[b * NSPLIT + k]);
    float L = 0.f;
    float sum = 0.f;
    for (int k = 0; k < nb; ++k) {
        float sc = __expf(m_part[b * NSPLIT + k] - M);
        L += sc * l_part[b * NSPLIT + k];
        sum += sc * ctxp[((size_t)(b * NSPLIT + k)) * DD + col];
    }
    ctx[(size_t)b * DD + col] = sum / L;
    if (threadIdx.x == 0 && (blockIdx.x & 3) == 0) { Mb[b] = M; Lb[b] = L; }
}

// ---------------- K5: out_part = cat([ctx,hidden]) @ W2^T (split-K) ----------------
__global__ __launch_bounds__(256) void k5_outgemm(const float* __restrict__ ctx,
                                                  const float* __restrict__ hidden,
                                                  const float* __restrict__ W2,
                                                  float* __restrict__ outp) {
    int dt = blockIdx.x & 31;
    int ks = blockIdx.x >> 5;
    int tid = threadIdx.x;
    __shared__ float cat_s[32 * 128];
    __shared__ float w2_s[32 * 128];
    int b0 = tid & 15, b1 = b0 + 16;
    int dl0 = (tid >> 4) * 2, dl1 = dl0 + 1;
    float acc00 = 0.f, acc01 = 0.f, acc10 = 0.f, acc11 = 0.f;

    int j0 = ks * 128;
#pragma unroll
    for (int pass = 0; pass < 4; ++pass) {
        int r = pass * 8 + (tid >> 5);
        int jj4 = tid & 31;
        int j = j0 + jj4 * 4;
        const float* src = (j < 1024) ? (ctx + (size_t)r * 1024 + j)
                                      : (hidden + (size_t)r * 1024 + (j - 1024));
        float4 v = *(const float4*)src;
        *(float4*)(cat_s + r * 128 + ((jj4 ^ (r & 7)) << 2)) = v;
        int dg = dt * 32 + r;
        float4 wv = *(const float4*)(W2 + (size_t)dg * HD + j);
        *(float4*)(w2_s + r * 128 + ((jj4 ^ (r & 7)) << 2)) = wv;
    }
    __syncthreads();
#pragma unroll 4
    for (int jj4 = 0; jj4 < 32; ++jj4) {
        float4 cA = *(const float4*)(cat_s + b0 * 128 + ((jj4 ^ (b0 & 7)) << 2));
        float4 cB = *(const float4*)(cat_s + b1 * 128 + ((jj4 ^ (b1 & 7)) << 2));
        float4 wA = *(const float4*)(w2_s + dl0 * 128 + ((jj4 ^ (dl0 & 7)) << 2));
        float4 wB = *(const float4*)(w2_s + dl1 * 128 + ((jj4 ^ (dl1 & 7)) << 2));
        acc00 += dot4(cA, wA);
        acc01 += dot4(cA, wB);
        acc10 += dot4(cB, wA);
        acc11 += dot4(cB, wB);
    }
    float* op = outp + (size_t)ks * (BB * DD);
    op[b0 * 1024 + dt * 32 + dl0] = acc00;
    op[b0 * 1024 + dt * 32 + dl1] = acc01;
    op[b1 * 1024 + dt * 32 + dl0] = acc10;
    op[b1 * 1024 + dt * 32 + dl1] = acc11;
}

// ---------------- K6: finalize: out = tanh(sum partials); attn.T ----------------
__global__ __launch_bounds__(256) void k6_final(const float* __restrict__ outp,
                                                const float* __restrict__ scores,
                                                const int* __restrict__ src_lens,
                                                const float* __restrict__ Mb,
                                                const float* __restrict__ Lb,
                                                float* __restrict__ out) {
    int i = blockIdx.x * 256 + threadIdx.x;
    if (i < BB * DD) {
        float s = 0.f;
#pragma unroll
        for (int k = 0; k < KSPLIT; ++k) s += outp[(size_t)k * (BB * DD) + i];
        out[i] = tanhf(s);
    } else {
        int j = i - BB * DD;           // attn.T index: j = s*B + b
        int b = j & 31, sIdx = j >> 5;
        float v = 0.0f;                // rows >= len: exp(-1e10 - M) == 0 exactly
        if (sIdx < src_lens[b]) v = __expf(scores[b * SS + sIdx] - Mb[b]) / Lb[b];
        out[i] = v;
    }
}

extern "C" void kernel_launch(void* const* d_in, const int* in_sizes, int n_in,
                              void* d_out, int out_size, void* d_ws, size_t ws_size,
                              hipStream_t stream) {
    const float* hidden = (const float*)d_in[0];
    const float* enc = (const float*)d_in[1];
    const int* src_lens = (const int*)d_in[2];
    const float* W1 = (const float*)d_in[3];
    const float* W2 = (const float*)d_in[4];
    float* out = (float*)d_out;
    float* ws = (float*)d_ws;

    // ws layout (floats)
    float* x = ws;                       // 32768
    float* scores = ws + 32768;          // 65536
    float* ctxp = ws + 98304;            // 32*32*1024 = 1048576
    float* m_part = ws + 1146880;        // 1024
    float* l_part = ws + 1147904;        // 1024
    float* Mb = ws + 1148928;            // 32
    float* Lb = ws + 1148960;            // 32
    float* ctx = ws + 1148992;           // 32768
    float* outp = ws + 1181760;          // 16*32768 = 524288  (total ~6.8 MB)

    k1_gemv_x<<<256, 256, 0, stream>>>(hidden, W1, x);
    k2_fused<<<512, 512, 0, stream>>>(enc, x, src_lens, scores, ctxp, m_part, l_part);
    k3_combine<<<128, 256, 0, stream>>>(ctxp, m_part, l_part, src_lens, ctx, Mb, Lb);
    k5_outgemm<<<512, 256, 0, stream>>>(ctx, hidden, W2, outp);
    k6_final<<<384, 256, 0, stream>>>(outp, scores, src_lens, Mb, Lb, out);
}